// Round 2
// baseline (513.549 us; speedup 1.0000x reference)
//
#include <hip/hip_runtime.h>
#include <stdint.h>
#include <stddef.h>

typedef __fp16 f16;
typedef __attribute__((ext_vector_type(8))) __fp16 half8;
typedef __attribute__((ext_vector_type(4))) float f32x4;

static __device__ __forceinline__ f32x4 mfma16(half8 a, half8 b, f32x4 c) {
    return __builtin_amdgcn_mfma_f32_16x16x32_f16(a, b, c, 0, 0, 0);
}
static __device__ __forceinline__ float sigm(float x) { return 1.f / (1.f + __expf(-x)); }
static __device__ __forceinline__ float tanh_(float x) { return 1.f - 2.f / (1.f + __expf(2.f * x)); }

// ---------------- workspace layout (bytes) ----------------
static constexpr size_t OFF_EMB   = 0;                       // 50000*32*2 = 3,200,000
static constexpr size_t OFF_WQIH  = 3200000;                 // 128*32*2
static constexpr size_t OFF_WQHH  = OFF_WQIH + 8192;
static constexpr size_t OFF_WSIH  = OFF_WQHH + 8192;
static constexpr size_t OFF_WSHH  = OFF_WSIH + 8192;
static constexpr size_t OFF_G1WP  = OFF_WSHH + 8192;         // 256*64*2
static constexpr size_t OFF_BIAS8 = OFF_G1WP + 32768;        // 8*256*4
static constexpr size_t OFF_G2W   = OFF_BIAS8 + 8192;        // 256*256*2
static constexpr size_t OFF_G3W   = OFF_G2W + 131072;
static constexpr size_t OFF_G4W   = OFF_G3W + 131072;
static constexpr size_t OFF_F1W   = OFF_G4W + 131072;
static constexpr size_t OFF_F2W   = OFF_F1W + 131072;        // 512*256*2
static constexpr size_t OFF_F3W   = OFF_F2W + 262144;        // 1000*512*2
static constexpr size_t OFF_HS    = OFF_F3W + 1024000;       // 32768*32*2
static constexpr size_t OFF_HQ    = OFF_HS + 2097152;        // 4096*32*2
static constexpr size_t OFF_ACT1  = OFF_HQ + 262144;         // 32768*256*2 = 16MB
static constexpr size_t OFF_ACT2  = OFF_ACT1 + 16777216;
static constexpr size_t WS_NEED   = OFF_ACT2 + 16777216;
// reuse of ACT1 region after g4:
static constexpr size_t OFF_GO    = OFF_ACT1;                // 4096*256*2
static constexpr size_t OFF_FA    = OFF_ACT1 + 2097152;      // 4096*256*2
static constexpr size_t OFF_FB    = OFF_ACT1 + 4194304;      // 4096*512*2

// ---------------- fp32 -> fp16 conversion (all tensors, one launch) ----------------
struct CvtJobs { const float* src[11]; f16* dst[11]; int n[11]; };

__global__ __launch_bounds__(256) void cvt_multi(CvtJobs j) {
    int t = blockIdx.y;
    int i = (blockIdx.x * 256 + threadIdx.x) * 8;
    if (i >= j.n[t]) return;
    const float* s = j.src[t] + i;
    f32x4 a = *(const f32x4*)s;
    f32x4 b = *(const f32x4*)(s + 4);
    half8 o;
    o[0]=(f16)a[0]; o[1]=(f16)a[1]; o[2]=(f16)a[2]; o[3]=(f16)a[3];
    o[4]=(f16)b[0]; o[5]=(f16)b[1]; o[6]=(f16)b[2]; o[7]=(f16)b[3];
    *(half8*)(j.dst[t] + i) = o;
}

// ---------------- g1 weight packing: [256][65] -> [256][64] fp16 + bias8[8][256] ----------------
__global__ __launch_bounds__(256) void prep_g1(const float* __restrict__ g1W, const float* __restrict__ g1b,
                                               f16* __restrict__ wp, float* __restrict__ bias8) {
    int col = threadIdx.x;  // 0..255
    for (int k = 0; k < 64; k++) wp[col * 64 + k] = (f16)g1W[col * 65 + k];
    float wpos = g1W[col * 65 + 64];
    float b = g1b[col];
    for (int i = 0; i < 8; i++) bias8[i * 256 + col] = b + (float)i * wpos;
}

// ---------------- fused LSTM (sf: samples 0..32767, q: 32768..36863) ----------------
struct SfPtrs { const int* p[8]; };

__global__ __launch_bounds__(256) void lstm_kernel(
    SfPtrs sf, const int* __restrict__ qtok, const f16* __restrict__ emb_h,
    const f16* __restrict__ wih_sf, const f16* __restrict__ whh_sf, const float* __restrict__ b_sf,
    const f16* __restrict__ wih_q,  const f16* __restrict__ whh_q,  const float* __restrict__ b_q,
    f16* __restrict__ hs_out, f16* __restrict__ hq_out)
{
    __shared__ __align__(16) char hbuf_s[4][16 * 80];   // per-wave h staging, 80B row stride
    int wave = threadIdx.x >> 6, lane = threadIdx.x & 63;
    int c15 = lane & 15, kq = lane >> 4;
    char* hb = hbuf_s[wave];
    int sbase = blockIdx.x * 64 + wave * 16;  // first sample of this wave
    bool isq = sbase >= 32768;
    const f16* wih = isq ? wih_q : wih_sf;
    const f16* whh = isq ? whh_q : whh_sf;
    const float* bvec = isq ? b_q : b_sf;

    // weight fragments: tile n covers gate-rows n*16..n*16+15 ; B[k][col] = W[col][k]
    half8 wi[8], wh[8];
    float bf[8];
    #pragma unroll
    for (int n = 0; n < 8; n++) {
        int col = n * 16 + c15;
        wi[n] = *(const half8*)(wih + col * 32 + kq * 8);
        wh[n] = *(const half8*)(whh + col * 32 + kq * 8);
        bf[n] = bvec[col];
    }
    // per-lane token pointer for sample (sbase + c15)
    int sg = sbase + c15;
    const int* tp;
    if (isq) tp = qtok + (sg - 32768) * 64;
    else     tp = sf.p[sg >> 12] + (sg & 4095) * 64;

    // zero h buffer (1280 B per wave)
    f32x4 zro = {0.f, 0.f, 0.f, 0.f};
    *(f32x4*)(hb + lane * 16) = zro;
    if (lane < 16) *(f32x4*)(hb + 1024 + lane * 16) = zro;
    asm volatile("s_waitcnt lgkmcnt(0)" ::: "memory");

    float cst[4][2] = {};
    const char* hrd = hb + c15 * 80 + kq * 16;

    int tok = tp[0];
    half8 xf = *(const half8*)(emb_h + (size_t)tok * 32 + kq * 8);

    #pragma unroll 1
    for (int t = 0; t < 64; t++) {
        half8 hf = *(const half8*)hrd;
        f32x4 acc[8];
        #pragma unroll
        for (int n = 0; n < 8; n++) acc[n] = mfma16(xf, wi[n], zro);
        #pragma unroll
        for (int n = 0; n < 8; n++) acc[n] = mfma16(hf, wh[n], acc[n]);
        // prefetch next-step x fragment (hidden under elementwise below)
        if (t < 63) {
            int tk = tp[t + 1];
            xf = *(const half8*)(emb_h + (size_t)tk * 32 + kq * 8);
        }
        // elementwise LSTM update: this lane owns samples kq*4+r, hidden units jh*16+c15
        #pragma unroll
        for (int r = 0; r < 4; r++) {
            #pragma unroll
            for (int jh = 0; jh < 2; jh++) {
                float xi = acc[0 + jh][r] + bf[0 + jh];
                float xv = acc[2 + jh][r] + bf[2 + jh];
                float xg = acc[4 + jh][r] + bf[4 + jh];
                float xo = acc[6 + jh][r] + bf[6 + jh];
                float si = sigm(xi), sfv = sigm(xv), so = sigm(xo);
                float tg = tanh_(xg);
                float cn = sfv * cst[r][jh] + si * tg;
                cst[r][jh] = cn;
                float hn = so * tanh_(cn);
                int s = kq * 4 + r, jj = jh * 16 + c15;
                *(f16*)(hb + s * 80 + jj * 2) = (f16)hn;
            }
        }
        asm volatile("s_waitcnt lgkmcnt(0)" ::: "memory");
    }
    // write final h: lane covers 16B chunk (row = lane>>2, chunk = lane&3)
    int row = lane >> 2, ch = lane & 3;
    half8 hv = *(const half8*)(hb + row * 80 + ch * 16);
    int so_ = sbase + row;
    if (isq) *(half8*)(hq_out + (size_t)(so_ - 32768) * 32 + ch * 8) = hv;
    else     *(half8*)(hs_out + (size_t)so_ * 32 + ch * 8) = hv;
}

// ---------------- g1: [32768 x 64] (hs||hq) @ Wp[256][64]^T + bias8[i], relu ----------------
__global__ __launch_bounds__(256) void gemm_g1(
    const f16* __restrict__ hs, const f16* __restrict__ hq,
    const f16* __restrict__ Wp, const float* __restrict__ bias8,
    f16* __restrict__ out)
{
    int wave = threadIdx.x >> 6, lane = threadIdx.x & 63;
    int c15 = lane & 15, kq = lane >> 4;
    int wm = wave >> 1, wn = wave & 1;
    int m0 = blockIdx.x * 128 + wm * 64;
    int n0 = blockIdx.y * 128 + wn * 64;
    const float* bias = bias8 + ((blockIdx.x * 128) >> 12) * 256;
    f32x4 zro = {0.f, 0.f, 0.f, 0.f};
    f32x4 acc[4][4];
    #pragma unroll
    for (int a = 0; a < 4; a++)
        #pragma unroll
        for (int b = 0; b < 4; b++) acc[a][b] = zro;

    half8 av[4], bv[4];
    // k-step 0: hs part
    #pragma unroll
    for (int fm = 0; fm < 4; fm++) av[fm] = *(const half8*)(hs + (size_t)(m0 + fm * 16 + c15) * 32 + kq * 8);
    #pragma unroll
    for (int fn = 0; fn < 4; fn++) bv[fn] = *(const half8*)(Wp + (size_t)(n0 + fn * 16 + c15) * 64 + kq * 8);
    #pragma unroll
    for (int fm = 0; fm < 4; fm++)
        #pragma unroll
        for (int fn = 0; fn < 4; fn++) acc[fm][fn] = mfma16(av[fm], bv[fn], acc[fm][fn]);
    // k-step 1: hq part (row & 4095 -> b)
    #pragma unroll
    for (int fm = 0; fm < 4; fm++) av[fm] = *(const half8*)(hq + (size_t)((m0 + fm * 16 + c15) & 4095) * 32 + kq * 8);
    #pragma unroll
    for (int fn = 0; fn < 4; fn++) bv[fn] = *(const half8*)(Wp + (size_t)(n0 + fn * 16 + c15) * 64 + 32 + kq * 8);
    #pragma unroll
    for (int fm = 0; fm < 4; fm++)
        #pragma unroll
        for (int fn = 0; fn < 4; fn++) acc[fm][fn] = mfma16(av[fm], bv[fn], acc[fm][fn]);
    // epilogue
    #pragma unroll
    for (int fn = 0; fn < 4; fn++) {
        int col = n0 + fn * 16 + c15;
        float bb = bias[col];
        #pragma unroll
        for (int fm = 0; fm < 4; fm++)
            #pragma unroll
            for (int r = 0; r < 4; r++) {
                int row = m0 + fm * 16 + kq * 4 + r;
                float v = acc[fm][fn][r] + bb;
                v = fmaxf(v, 0.f);
                out[(size_t)row * 256 + col] = (f16)v;
            }
    }
}

// ---------------- generic GEMM: Y[M][N] = relu?(X[M][K] @ W[N][K]^T + b) ----------------
template<int K, bool RELU, bool OUTF32>
__global__ __launch_bounds__(256) void gemm_k(
    const f16* __restrict__ A, const f16* __restrict__ W, const float* __restrict__ bias,
    void* __restrict__ outv, int N, int ldout)
{
    int wave = threadIdx.x >> 6, lane = threadIdx.x & 63;
    int c15 = lane & 15, kq = lane >> 4;
    int wm = wave >> 1, wn = wave & 1;
    int m0 = blockIdx.x * 128 + wm * 64;
    int n0 = blockIdx.y * 128 + wn * 64;
    f32x4 zro = {0.f, 0.f, 0.f, 0.f};
    f32x4 acc[4][4];
    #pragma unroll
    for (int a = 0; a < 4; a++)
        #pragma unroll
        for (int b = 0; b < 4; b++) acc[a][b] = zro;

    const f16* ap[4];
    const f16* bp[4];
    #pragma unroll
    for (int fm = 0; fm < 4; fm++) ap[fm] = A + (size_t)(m0 + fm * 16 + c15) * K + kq * 8;
    #pragma unroll
    for (int fn = 0; fn < 4; fn++) {
        int col = n0 + fn * 16 + c15;
        if (col > N - 1) col = N - 1;
        bp[fn] = W + (size_t)col * K + kq * 8;
    }
    for (int k0 = 0; k0 < K; k0 += 32) {
        half8 av[4], bv[4];
        #pragma unroll
        for (int fm = 0; fm < 4; fm++) av[fm] = *(const half8*)(ap[fm] + k0);
        #pragma unroll
        for (int fn = 0; fn < 4; fn++) bv[fn] = *(const half8*)(bp[fn] + k0);
        #pragma unroll
        for (int fm = 0; fm < 4; fm++)
            #pragma unroll
            for (int fn = 0; fn < 4; fn++) acc[fm][fn] = mfma16(av[fm], bv[fn], acc[fm][fn]);
    }
    #pragma unroll
    for (int fn = 0; fn < 4; fn++) {
        int col = n0 + fn * 16 + c15;
        if (col < N) {
            float bb = bias[col];
            #pragma unroll
            for (int fm = 0; fm < 4; fm++)
                #pragma unroll
                for (int r = 0; r < 4; r++) {
                    int row = m0 + fm * 16 + kq * 4 + r;
                    float v = acc[fm][fn][r] + bb;
                    if (RELU) v = fmaxf(v, 0.f);
                    if (OUTF32) ((float*)outv)[(size_t)row * ldout + col] = v;
                    else ((f16*)outv)[(size_t)row * ldout + col] = (f16)v;
                }
        }
    }
}

// ---------------- segment-sum over the 8 relations ----------------
__global__ __launch_bounds__(256) void sum8_kernel(const f16* __restrict__ g4o, f16* __restrict__ go) {
    int t = blockIdx.x * 256 + threadIdx.x;   // 131072 threads
    int b = t >> 5, chk = t & 31;
    const f16* p = g4o + (size_t)b * 256 + chk * 8;
    float a[8] = {};
    #pragma unroll
    for (int i = 0; i < 8; i++) {
        half8 v = *(const half8*)(p + (size_t)i * 4096 * 256);
        #pragma unroll
        for (int j = 0; j < 8; j++) a[j] += (float)v[j];
    }
    half8 o;
    #pragma unroll
    for (int j = 0; j < 8; j++) o[j] = (f16)a[j];
    *(half8*)(go + (size_t)b * 256 + chk * 8) = o;
}

// ---------------- launcher ----------------
extern "C" void kernel_launch(void* const* d_in, const int* in_sizes, int n_in,
                              void* d_out, int out_size, void* d_ws, size_t ws_size,
                              hipStream_t stream)
{
    if (ws_size < WS_NEED) return;  // workspace too small -> fail visibly
    const int* q_tok = (const int*)d_in[0];
    SfPtrs sf;
    for (int i = 0; i < 8; i++) sf.p[i] = (const int*)d_in[1 + i];
    const float* emb_f = (const float*)d_in[9];
    const float* qWih = (const float*)d_in[10];
    const float* qWhh = (const float*)d_in[11];
    const float* q_b  = (const float*)d_in[12];
    const float* sWih = (const float*)d_in[13];
    const float* sWhh = (const float*)d_in[14];
    const float* s_b  = (const float*)d_in[15];
    const float* g1W  = (const float*)d_in[16];
    const float* g1b  = (const float*)d_in[17];
    const float* g2W  = (const float*)d_in[18];
    const float* g2b  = (const float*)d_in[19];
    const float* g3W  = (const float*)d_in[20];
    const float* g3b  = (const float*)d_in[21];
    const float* g4W  = (const float*)d_in[22];
    const float* g4b  = (const float*)d_in[23];
    const float* f1W  = (const float*)d_in[24];
    const float* f1b  = (const float*)d_in[25];
    const float* f2W  = (const float*)d_in[26];
    const float* f2b  = (const float*)d_in[27];
    const float* f3W  = (const float*)d_in[28];
    const float* f3b  = (const float*)d_in[29];

    char* ws = (char*)d_ws;
    f16* emb_h = (f16*)(ws + OFF_EMB);
    f16* wqih  = (f16*)(ws + OFF_WQIH);
    f16* wqhh  = (f16*)(ws + OFF_WQHH);
    f16* wsih  = (f16*)(ws + OFF_WSIH);
    f16* wshh  = (f16*)(ws + OFF_WSHH);
    f16* g1wp  = (f16*)(ws + OFF_G1WP);
    float* bias8 = (float*)(ws + OFF_BIAS8);
    f16* g2w = (f16*)(ws + OFF_G2W);
    f16* g3w = (f16*)(ws + OFF_G3W);
    f16* g4w = (f16*)(ws + OFF_G4W);
    f16* f1w = (f16*)(ws + OFF_F1W);
    f16* f2w = (f16*)(ws + OFF_F2W);
    f16* f3w = (f16*)(ws + OFF_F3W);
    f16* hs  = (f16*)(ws + OFF_HS);
    f16* hq  = (f16*)(ws + OFF_HQ);
    f16* act1 = (f16*)(ws + OFF_ACT1);
    f16* act2 = (f16*)(ws + OFF_ACT2);
    f16* go = (f16*)(ws + OFF_GO);
    f16* fa = (f16*)(ws + OFF_FA);
    f16* fb = (f16*)(ws + OFF_FB);

    CvtJobs cj;
    const float* srcs[11] = {emb_f, qWih, qWhh, sWih, sWhh, g2W, g3W, g4W, f1W, f2W, f3W};
    f16* dsts[11]         = {emb_h, wqih, wqhh, wsih, wshh, g2w, g3w, g4w, f1w, f2w, f3w};
    int ns[11] = {1600000, 4096, 4096, 4096, 4096, 65536, 65536, 65536, 65536, 131072, 512000};
    for (int i = 0; i < 11; i++) { cj.src[i] = srcs[i]; cj.dst[i] = dsts[i]; cj.n[i] = ns[i]; }

    cvt_multi<<<dim3(782, 11), 256, 0, stream>>>(cj);
    prep_g1<<<1, 256, 0, stream>>>(g1W, g1b, g1wp, bias8);
    lstm_kernel<<<576, 256, 0, stream>>>(sf, q_tok, emb_h, wsih, wshh, s_b, wqih, wqhh, q_b, hs, hq);
    gemm_g1<<<dim3(256, 2), 256, 0, stream>>>(hs, hq, g1wp, bias8, act1);
    gemm_k<256, true, false><<<dim3(256, 2), 256, 0, stream>>>(act1, g2w, g2b, act2, 256, 256);
    gemm_k<256, true, false><<<dim3(256, 2), 256, 0, stream>>>(act2, g3w, g3b, act1, 256, 256);
    gemm_k<256, true, false><<<dim3(256, 2), 256, 0, stream>>>(act1, g4w, g4b, act2, 256, 256);
    sum8_kernel<<<512, 256, 0, stream>>>(act2, go);
    gemm_k<256, true, false><<<dim3(32, 2), 256, 0, stream>>>(go, f1w, f1b, fa, 256, 256);
    gemm_k<256, true, false><<<dim3(32, 4), 256, 0, stream>>>(fa, f2w, f2b, fb, 512, 512);
    gemm_k<512, false, true><<<dim3(32, 8), 256, 0, stream>>>(fb, f3w, f3b, d_out, 1000, 1000);
}

// Round 3
// 373.260 us; speedup vs baseline: 1.3758x; 1.3758x over previous
//
#include <hip/hip_runtime.h>
#include <stdint.h>
#include <stddef.h>

typedef __fp16 f16;
typedef __attribute__((ext_vector_type(8))) __fp16 half8;
typedef __attribute__((ext_vector_type(4))) float f32x4;

static __device__ __forceinline__ f32x4 mfma16(half8 a, half8 b, f32x4 c) {
    return __builtin_amdgcn_mfma_f32_16x16x32_f16(a, b, c, 0, 0, 0);
}
// raw HW transcendentals (1-ulp approx, plenty for f16 outputs)
static __device__ __forceinline__ float fexp2(float x) { float r; asm("v_exp_f32 %0, %1" : "=v"(r) : "v"(x)); return r; }
static __device__ __forceinline__ float frcp(float x)  { float r; asm("v_rcp_f32 %0, %1" : "=v"(r) : "v"(x)); return r; }

static constexpr float L2E  = 1.4426950408889634f;   // log2(e)
static constexpr float L2E2 = 2.8853900817779268f;   // 2*log2(e)

// ---------------- workspace layout (bytes) ----------------
static constexpr size_t OFF_EMB   = 0;                       // 50000*32*2 = 3,200,000
static constexpr size_t OFF_WQIH  = 3200000;                 // 128*32*2 (scaled)
static constexpr size_t OFF_WQHH  = OFF_WQIH + 8192;
static constexpr size_t OFF_WSIH  = OFF_WQHH + 8192;
static constexpr size_t OFF_WSHH  = OFF_WSIH + 8192;
static constexpr size_t OFF_BQ    = OFF_WSHH + 8192;         // 128*4 (scaled, f32)
static constexpr size_t OFF_BS    = OFF_BQ + 512;
static constexpr size_t OFF_G1WP  = OFF_BS + 512;            // 256*64*2
static constexpr size_t OFF_BIAS8 = OFF_G1WP + 32768;        // 8*256*4
static constexpr size_t OFF_G2W   = OFF_BIAS8 + 8192;        // 256*256*2
static constexpr size_t OFF_G3W   = OFF_G2W + 131072;
static constexpr size_t OFF_G4W   = OFF_G3W + 131072;
static constexpr size_t OFF_F1W   = OFF_G4W + 131072;
static constexpr size_t OFF_F2W   = OFF_F1W + 131072;        // 512*256*2
static constexpr size_t OFF_F3W   = OFF_F2W + 262144;        // 1000*512*2
static constexpr size_t OFF_HS    = OFF_F3W + 1024000;       // 32768*32*2
static constexpr size_t OFF_HQ    = OFF_HS + 2097152;        // 4096*32*2
static constexpr size_t OFF_ACT1  = OFF_HQ + 262144;         // 32768*256*2 = 16MB
static constexpr size_t OFF_ACT2  = OFF_ACT1 + 16777216;
static constexpr size_t WS_NEED   = OFF_ACT2 + 16777216;
// reuse of ACT1 region after g4:
static constexpr size_t OFF_GO    = OFF_ACT1;                // 4096*256*2
static constexpr size_t OFF_FA    = OFF_ACT1 + 2097152;      // 4096*256*2
static constexpr size_t OFF_FB    = OFF_ACT1 + 4194304;      // 4096*512*2

// ---------------- fp32 -> fp16 conversion (bulk tensors) ----------------
struct CvtJobs { const float* src[7]; f16* dst[7]; int n[7]; };

__global__ __launch_bounds__(256) void cvt_multi(CvtJobs j) {
    int t = blockIdx.y;
    int i = (blockIdx.x * 256 + threadIdx.x) * 8;
    if (i >= j.n[t]) return;
    const float* s = j.src[t] + i;
    f32x4 a = *(const f32x4*)s;
    f32x4 b = *(const f32x4*)(s + 4);
    half8 o;
    o[0]=(f16)a[0]; o[1]=(f16)a[1]; o[2]=(f16)a[2]; o[3]=(f16)a[3];
    o[4]=(f16)b[0]; o[5]=(f16)b[1]; o[6]=(f16)b[2]; o[7]=(f16)b[3];
    *(half8*)(j.dst[t] + i) = o;
}

// ---------------- small prep: g1 pack + LSTM weight prescale ----------------
// block 0: g1 [256][65] -> [256][64] fp16 + bias8[8][256]
// block 1: LSTM Wih/Whh/b scaled by -log2e (i,f,o rows) / +2log2e (g rows)
__global__ __launch_bounds__(256) void prep_small(
    const float* __restrict__ g1W, const float* __restrict__ g1b,
    f16* __restrict__ wp, float* __restrict__ bias8,
    const float* __restrict__ qWih, const float* __restrict__ qWhh, const float* __restrict__ qb,
    const float* __restrict__ sWih, const float* __restrict__ sWhh, const float* __restrict__ sb,
    f16* __restrict__ wqih, f16* __restrict__ wqhh, float* __restrict__ bq,
    f16* __restrict__ wsih, f16* __restrict__ wshh, float* __restrict__ bs)
{
    int t = threadIdx.x;
    if (blockIdx.x == 0) {
        int col = t;  // 0..255
        for (int k = 0; k < 64; k++) wp[col * 64 + k] = (f16)g1W[col * 65 + k];
        float wpos = g1W[col * 65 + 64];
        float b = g1b[col];
        for (int i = 0; i < 8; i++) bias8[i * 256 + col] = b + (float)i * wpos;
    } else {
        for (int i = t; i < 4096; i += 256) {
            int row = i >> 5;
            float s = (row < 64 || row >= 96) ? -L2E : L2E2;   // i,f,o : g
            wqih[i] = (f16)(qWih[i] * s);
            wqhh[i] = (f16)(qWhh[i] * s);
            wsih[i] = (f16)(sWih[i] * s);
            wshh[i] = (f16)(sWhh[i] * s);
        }
        if (t < 128) {
            float s = (t < 64 || t >= 96) ? -L2E : L2E2;
            bq[t] = qb[t] * s;
            bs[t] = sb[t] * s;
        }
    }
}

// ---------------- fused LSTM: one wave = 16 samples (sf: 0..32767, q: 32768..36863) ----------------
struct SfPtrs { const int* p[8]; };

__global__ __launch_bounds__(64) void lstm_kernel(
    SfPtrs sf, const int* __restrict__ qtok, const f16* __restrict__ emb_h,
    const f16* __restrict__ wih_sf, const f16* __restrict__ whh_sf, const float* __restrict__ b_sf,
    const f16* __restrict__ wih_q,  const f16* __restrict__ whh_q,  const float* __restrict__ b_q,
    f16* __restrict__ hs_out, f16* __restrict__ hq_out)
{
    __shared__ __align__(16) char hb[16 * 80];   // h staging, 80B row stride
    int lane = threadIdx.x;
    int c15 = lane & 15, kq = lane >> 4;
    int sbase = blockIdx.x * 16;  // first sample of this wave
    bool isq = sbase >= 32768;
    const f16* wih = isq ? wih_q : wih_sf;
    const f16* whh = isq ? whh_q : whh_sf;
    const float* bvec = isq ? b_q : b_sf;

    // weight fragments: tile n covers gate-rows n*16..n*16+15 ; B[k][col] = W[col][k]
    half8 wi[8], wh[8];
    f32x4 bc[8];
    #pragma unroll
    for (int n = 0; n < 8; n++) {
        int col = n * 16 + c15;
        wi[n] = *(const half8*)(wih + col * 32 + kq * 8);
        wh[n] = *(const half8*)(whh + col * 32 + kq * 8);
        float b = bvec[col];
        bc[n][0] = b; bc[n][1] = b; bc[n][2] = b; bc[n][3] = b;
    }
    // per-lane token pointer for sample (sbase + c15)
    int sg = sbase + c15;
    const int* tp;
    if (isq) tp = qtok + (sg - 32768) * 64;
    else     tp = sf.p[sg >> 12] + (sg & 4095) * 64;

    // zero h buffer (1280 B)
    f32x4 zro = {0.f, 0.f, 0.f, 0.f};
    *(f32x4*)(hb + lane * 16) = zro;
    if (lane < 16) *(f32x4*)(hb + 1024 + lane * 16) = zro;
    asm volatile("s_waitcnt lgkmcnt(0)" ::: "memory");

    float cst[4][2] = {};
    const char* hrd = hb + c15 * 80 + kq * 16;

    int tok = tp[0];
    half8 xf = *(const half8*)(emb_h + (size_t)tok * 32 + kq * 8);

    #pragma unroll 1
    for (int t = 0; t < 64; t++) {
        half8 hf = *(const half8*)hrd;
        f32x4 acc[8];
        #pragma unroll
        for (int n = 0; n < 8; n++) acc[n] = mfma16(xf, wi[n], bc[n]);
        #pragma unroll
        for (int n = 0; n < 8; n++) acc[n] = mfma16(hf, wh[n], acc[n]);
        // prefetch next-step x fragment (hidden under elementwise below)
        if (t < 63) {
            int tk = tp[t + 1];
            xf = *(const half8*)(emb_h + (size_t)tk * 32 + kq * 8);
        }
        // gate math: acc_i/f/o = -log2e*gate, acc_g = +2log2e*gate (prescaled W,b)
        // lane owns samples kq*4+r, hidden units jh*16+c15
        #pragma unroll
        for (int r = 0; r < 4; r++) {
            #pragma unroll
            for (int jh = 0; jh < 2; jh++) {
                float ei = fexp2(acc[0 + jh][r]);
                float ef = fexp2(acc[2 + jh][r]);
                float eg = fexp2(acc[4 + jh][r]);
                float eo = fexp2(acc[6 + jh][r]);
                float si  = frcp(1.f + ei);           // sigmoid(i)
                float sfv = frcp(1.f + ef);           // sigmoid(f)
                float so  = frcp(1.f + eo);           // sigmoid(o)
                float tg  = fmaf(-2.f, frcp(1.f + eg), 1.f);   // tanh(g)
                float cn  = fmaf(sfv, cst[r][jh], si * tg);
                cst[r][jh] = cn;
                float e2  = fexp2(cn * L2E2);
                float th  = fmaf(-2.f, frcp(1.f + e2), 1.f);   // tanh(c)
                float hn  = so * th;
                *(f16*)(hb + (kq * 4 + r) * 80 + (jh * 16 + c15) * 2) = (f16)hn;
            }
        }
        asm volatile("s_waitcnt lgkmcnt(0)" ::: "memory");
    }
    // write final h: lane covers 16B chunk (row = lane>>2, chunk = lane&3)
    int row = lane >> 2, ch = lane & 3;
    half8 hv = *(const half8*)(hb + row * 80 + ch * 16);
    int so_ = sbase + row;
    if (isq) *(half8*)(hq_out + (size_t)(so_ - 32768) * 32 + ch * 8) = hv;
    else     *(half8*)(hs_out + (size_t)so_ * 32 + ch * 8) = hv;
}

// ---------------- g1: [32768 x 64] (hs||hq) @ Wp[256][64]^T + bias8[i], relu ----------------
__global__ __launch_bounds__(256) void gemm_g1(
    const f16* __restrict__ hs, const f16* __restrict__ hq,
    const f16* __restrict__ Wp, const float* __restrict__ bias8,
    f16* __restrict__ out)
{
    int wave = threadIdx.x >> 6, lane = threadIdx.x & 63;
    int c15 = lane & 15, kq = lane >> 4;
    int wm = wave >> 1, wn = wave & 1;
    int m0 = blockIdx.x * 128 + wm * 64;
    int n0 = blockIdx.y * 128 + wn * 64;
    const float* bias = bias8 + ((blockIdx.x * 128) >> 12) * 256;
    f32x4 zro = {0.f, 0.f, 0.f, 0.f};
    f32x4 acc[4][4];
    #pragma unroll
    for (int a = 0; a < 4; a++)
        #pragma unroll
        for (int b = 0; b < 4; b++) acc[a][b] = zro;

    half8 av[4], bv[4];
    #pragma unroll
    for (int fm = 0; fm < 4; fm++) av[fm] = *(const half8*)(hs + (size_t)(m0 + fm * 16 + c15) * 32 + kq * 8);
    #pragma unroll
    for (int fn = 0; fn < 4; fn++) bv[fn] = *(const half8*)(Wp + (size_t)(n0 + fn * 16 + c15) * 64 + kq * 8);
    #pragma unroll
    for (int fm = 0; fm < 4; fm++)
        #pragma unroll
        for (int fn = 0; fn < 4; fn++) acc[fm][fn] = mfma16(av[fm], bv[fn], acc[fm][fn]);
    #pragma unroll
    for (int fm = 0; fm < 4; fm++) av[fm] = *(const half8*)(hq + (size_t)((m0 + fm * 16 + c15) & 4095) * 32 + kq * 8);
    #pragma unroll
    for (int fn = 0; fn < 4; fn++) bv[fn] = *(const half8*)(Wp + (size_t)(n0 + fn * 16 + c15) * 64 + 32 + kq * 8);
    #pragma unroll
    for (int fm = 0; fm < 4; fm++)
        #pragma unroll
        for (int fn = 0; fn < 4; fn++) acc[fm][fn] = mfma16(av[fm], bv[fn], acc[fm][fn]);
    #pragma unroll
    for (int fn = 0; fn < 4; fn++) {
        int col = n0 + fn * 16 + c15;
        float bb = bias[col];
        #pragma unroll
        for (int fm = 0; fm < 4; fm++)
            #pragma unroll
            for (int r = 0; r < 4; r++) {
                int row = m0 + fm * 16 + kq * 4 + r;
                float v = acc[fm][fn][r] + bb;
                v = fmaxf(v, 0.f);
                out[(size_t)row * 256 + col] = (f16)v;
            }
    }
}

// ---------------- generic GEMM: Y[M][N] = relu?(X[M][K] @ W[N][K]^T + b) ----------------
template<int K, bool RELU, bool OUTF32>
__global__ __launch_bounds__(256) void gemm_k(
    const f16* __restrict__ A, const f16* __restrict__ W, const float* __restrict__ bias,
    void* __restrict__ outv, int N, int ldout)
{
    int wave = threadIdx.x >> 6, lane = threadIdx.x & 63;
    int c15 = lane & 15, kq = lane >> 4;
    int wm = wave >> 1, wn = wave & 1;
    int m0 = blockIdx.x * 128 + wm * 64;
    int n0 = blockIdx.y * 128 + wn * 64;
    f32x4 zro = {0.f, 0.f, 0.f, 0.f};
    f32x4 acc[4][4];
    #pragma unroll
    for (int a = 0; a < 4; a++)
        #pragma unroll
        for (int b = 0; b < 4; b++) acc[a][b] = zro;

    const f16* ap[4];
    const f16* bp[4];
    #pragma unroll
    for (int fm = 0; fm < 4; fm++) ap[fm] = A + (size_t)(m0 + fm * 16 + c15) * K + kq * 8;
    #pragma unroll
    for (int fn = 0; fn < 4; fn++) {
        int col = n0 + fn * 16 + c15;
        if (col > N - 1) col = N - 1;
        bp[fn] = W + (size_t)col * K + kq * 8;
    }
    for (int k0 = 0; k0 < K; k0 += 32) {
        half8 av[4], bv[4];
        #pragma unroll
        for (int fm = 0; fm < 4; fm++) av[fm] = *(const half8*)(ap[fm] + k0);
        #pragma unroll
        for (int fn = 0; fn < 4; fn++) bv[fn] = *(const half8*)(bp[fn] + k0);
        #pragma unroll
        for (int fm = 0; fm < 4; fm++)
            #pragma unroll
            for (int fn = 0; fn < 4; fn++) acc[fm][fn] = mfma16(av[fm], bv[fn], acc[fm][fn]);
    }
    #pragma unroll
    for (int fn = 0; fn < 4; fn++) {
        int col = n0 + fn * 16 + c15;
        if (col < N) {
            float bb = bias[col];
            #pragma unroll
            for (int fm = 0; fm < 4; fm++)
                #pragma unroll
                for (int r = 0; r < 4; r++) {
                    int row = m0 + fm * 16 + kq * 4 + r;
                    float v = acc[fm][fn][r] + bb;
                    if (RELU) v = fmaxf(v, 0.f);
                    if (OUTF32) ((float*)outv)[(size_t)row * ldout + col] = v;
                    else ((f16*)outv)[(size_t)row * ldout + col] = (f16)v;
                }
        }
    }
}

// ---------------- segment-sum over the 8 relations ----------------
__global__ __launch_bounds__(256) void sum8_kernel(const f16* __restrict__ g4o, f16* __restrict__ go) {
    int t = blockIdx.x * 256 + threadIdx.x;   // 131072 threads
    int b = t >> 5, chk = t & 31;
    const f16* p = g4o + (size_t)b * 256 + chk * 8;
    float a[8] = {};
    #pragma unroll
    for (int i = 0; i < 8; i++) {
        half8 v = *(const half8*)(p + (size_t)i * 4096 * 256);
        #pragma unroll
        for (int j = 0; j < 8; j++) a[j] += (float)v[j];
    }
    half8 o;
    #pragma unroll
    for (int j = 0; j < 8; j++) o[j] = (f16)a[j];
    *(half8*)(go + (size_t)b * 256 + chk * 8) = o;
}

// ---------------- launcher ----------------
extern "C" void kernel_launch(void* const* d_in, const int* in_sizes, int n_in,
                              void* d_out, int out_size, void* d_ws, size_t ws_size,
                              hipStream_t stream)
{
    if (ws_size < WS_NEED) return;  // workspace too small -> fail visibly
    const int* q_tok = (const int*)d_in[0];
    SfPtrs sf;
    for (int i = 0; i < 8; i++) sf.p[i] = (const int*)d_in[1 + i];
    const float* emb_f = (const float*)d_in[9];
    const float* qWih = (const float*)d_in[10];
    const float* qWhh = (const float*)d_in[11];
    const float* q_b  = (const float*)d_in[12];
    const float* sWih = (const float*)d_in[13];
    const float* sWhh = (const float*)d_in[14];
    const float* s_b  = (const float*)d_in[15];
    const float* g1W  = (const float*)d_in[16];
    const float* g1b  = (const float*)d_in[17];
    const float* g2W  = (const float*)d_in[18];
    const float* g2b  = (const float*)d_in[19];
    const float* g3W  = (const float*)d_in[20];
    const float* g3b  = (const float*)d_in[21];
    const float* g4W  = (const float*)d_in[22];
    const float* g4b  = (const float*)d_in[23];
    const float* f1W  = (const float*)d_in[24];
    const float* f1b  = (const float*)d_in[25];
    const float* f2W  = (const float*)d_in[26];
    const float* f2b  = (const float*)d_in[27];
    const float* f3W  = (const float*)d_in[28];
    const float* f3b  = (const float*)d_in[29];

    char* ws = (char*)d_ws;
    f16* emb_h = (f16*)(ws + OFF_EMB);
    f16* wqih  = (f16*)(ws + OFF_WQIH);
    f16* wqhh  = (f16*)(ws + OFF_WQHH);
    f16* wsih  = (f16*)(ws + OFF_WSIH);
    f16* wshh  = (f16*)(ws + OFF_WSHH);
    float* bq  = (float*)(ws + OFF_BQ);
    float* bs  = (float*)(ws + OFF_BS);
    f16* g1wp  = (f16*)(ws + OFF_G1WP);
    float* bias8 = (float*)(ws + OFF_BIAS8);
    f16* g2w = (f16*)(ws + OFF_G2W);
    f16* g3w = (f16*)(ws + OFF_G3W);
    f16* g4w = (f16*)(ws + OFF_G4W);
    f16* f1w = (f16*)(ws + OFF_F1W);
    f16* f2w = (f16*)(ws + OFF_F2W);
    f16* f3w = (f16*)(ws + OFF_F3W);
    f16* hs  = (f16*)(ws + OFF_HS);
    f16* hq  = (f16*)(ws + OFF_HQ);
    f16* act1 = (f16*)(ws + OFF_ACT1);
    f16* act2 = (f16*)(ws + OFF_ACT2);
    f16* go = (f16*)(ws + OFF_GO);
    f16* fa = (f16*)(ws + OFF_FA);
    f16* fb = (f16*)(ws + OFF_FB);

    CvtJobs cj;
    const float* srcs[7] = {emb_f, g2W, g3W, g4W, f1W, f2W, f3W};
    f16* dsts[7]         = {emb_h, g2w, g3w, g4w, f1w, f2w, f3w};
    int ns[7] = {1600000, 65536, 65536, 65536, 65536, 131072, 512000};
    for (int i = 0; i < 7; i++) { cj.src[i] = srcs[i]; cj.dst[i] = dsts[i]; cj.n[i] = ns[i]; }

    cvt_multi<<<dim3(782, 7), 256, 0, stream>>>(cj);
    prep_small<<<2, 256, 0, stream>>>(g1W, g1b, g1wp, bias8,
                                      qWih, qWhh, q_b, sWih, sWhh, s_b,
                                      wqih, wqhh, bq, wsih, wshh, bs);
    lstm_kernel<<<2304, 64, 0, stream>>>(sf, q_tok, emb_h, wsih, wshh, bs, wqih, wqhh, bq, hs, hq);
    gemm_g1<<<dim3(256, 2), 256, 0, stream>>>(hs, hq, g1wp, bias8, act1);
    gemm_k<256, true, false><<<dim3(256, 2), 256, 0, stream>>>(act1, g2w, g2b, act2, 256, 256);
    gemm_k<256, true, false><<<dim3(256, 2), 256, 0, stream>>>(act2, g3w, g3b, act1, 256, 256);
    gemm_k<256, true, false><<<dim3(256, 2), 256, 0, stream>>>(act1, g4w, g4b, act2, 256, 256);
    sum8_kernel<<<512, 256, 0, stream>>>(act2, go);
    gemm_k<256, true, false><<<dim3(32, 2), 256, 0, stream>>>(go, f1w, f1b, fa, 256, 256);
    gemm_k<256, true, false><<<dim3(32, 4), 256, 0, stream>>>(fa, f2w, f2b, fb, 512, 512);
    gemm_k<512, false, true><<<dim3(32, 8), 256, 0, stream>>>(fb, f3w, f3b, d_out, 1000, 1000);
}